// Round 13
// baseline (442.253 us; speedup 1.0000x reference)
//
#include <hip/hip_runtime.h>
#include <hip/hip_bf16.h>
#include <math.h>

#define N_USERS 50000
#define N_ITEMS 100000
#define N_NODES 150000
#define N_EDGES 2000000
#define EMBED 64
#define N_LAYERS 3
#define BATCH 8192
#define BATCH3 (3 * BATCH)                                // 24576 truncated rows

#define BSHIFT 9
#define BROWS 512                                         // rows per bucket
#define NBKT ((N_NODES + BROWS - 1) / BROWS)              // 293
#define EPB 4096                                          // edges per phase-A block

typedef __bf16 bf16x8 __attribute__((ext_vector_type(8)));
typedef float  f32x4  __attribute__((ext_vector_type(4)));

__device__ __forceinline__ float bf2f(unsigned short u) {
    union { unsigned int i; float f; } c; c.i = ((unsigned int)u) << 16; return c.f;
}
__device__ __forceinline__ unsigned short f2bf(float f) {
    __hip_bfloat16 h = __float2bfloat16(f);               // RNE
    union { __hip_bfloat16 h; unsigned short u; } c; c.h = h; return c.u;
}
__device__ __forceinline__ unsigned char f2q8(float x) {  // f32 -> fp8 e4m3 (RNE)
    return (unsigned char)(__builtin_amdgcn_cvt_pk_fp8_f32(x, x, 0, false) & 0xff);
}
__device__ __forceinline__ bf16x8 as_bf8(uint4 u) {
    union { uint4 u; bf16x8 v; } c; c.u = u; return c.v;
}
__device__ __forceinline__ void unpack8(uint4 u, float* f) {
    union { unsigned int i; float x; } c;
    c.i = u.x << 16; f[0] = c.x; c.i = u.x & 0xffff0000u; f[1] = c.x;
    c.i = u.y << 16; f[2] = c.x; c.i = u.y & 0xffff0000u; f[3] = c.x;
    c.i = u.z << 16; f[4] = c.x; c.i = u.z & 0xffff0000u; f[5] = c.x;
    c.i = u.w << 16; f[6] = c.x; c.i = u.w & 0xffff0000u; f[7] = c.x;
}
__device__ __forceinline__ bf16x8 pack8(const float* f) {
    union { unsigned short s[8]; bf16x8 v; } u;
#pragma unroll
    for (int j = 0; j < 8; j++) u.s[j] = f2bf(f[j]);
    return u.v;
}
// 8 fp8 (uint2) gather-accumulate: acc[0..7] += v * vals
__device__ __forceinline__ void qacc8(uint2 w, float v, float* acc) {
    auto f0 = __builtin_amdgcn_cvt_pk_f32_fp8(w.x, false);
    auto f1 = __builtin_amdgcn_cvt_pk_f32_fp8(w.x, true);
    auto f2 = __builtin_amdgcn_cvt_pk_f32_fp8(w.y, false);
    auto f3 = __builtin_amdgcn_cvt_pk_f32_fp8(w.y, true);
    acc[0] += v * f0[0]; acc[1] += v * f0[1];
    acc[2] += v * f1[0]; acc[3] += v * f1[1];
    acc[4] += v * f2[0]; acc[5] += v * f2[1];
    acc[6] += v * f3[0]; acc[7] += v * f3[1];
}
// 16 fp8 (uint4) gather-accumulate: acc[0..15] += v * vals
__device__ __forceinline__ void qacc16(uint4 w, float v, float* acc) {
    qacc8(make_uint2(w.x, w.y), v, acc);
    qacc8(make_uint2(w.z, w.w), v, acc + 8);
}

// ---------------- build bf16 + fp8 tables from split f32 inputs ----------------
__global__ __launch_bounds__(256) void k_tabs(const float4* __restrict__ ue,
                                              const float4* __restrict__ ie,
                                              ushort4* __restrict__ tab,
                                              unsigned int* __restrict__ q8) {
    int idx = blockIdx.x * 256 + threadIdx.x;             // float4 index
    const int TOT = N_NODES * EMBED / 4;                  // 2,400,000
    const int UPART = N_USERS * EMBED / 4;                // 800,000
    if (idx < TOT) {
        float4 v = (idx < UPART) ? ue[idx] : ie[idx - UPART];
        ushort4 o;
        o.x = f2bf(v.x); o.y = f2bf(v.y); o.z = f2bf(v.z); o.w = f2bf(v.w);
        tab[idx] = o;
        unsigned int lo = (unsigned int)__builtin_amdgcn_cvt_pk_fp8_f32(v.x, v.y, 0, false) & 0xffffu;
        unsigned int hi = (unsigned int)__builtin_amdgcn_cvt_pk_fp8_f32(v.z, v.w, 0, false) & 0xffffu;
        q8[idx] = lo | (hi << 16);
    }
}

// ---------------- pack [W1;W2] into bf16 Wb[l][n][k0..127] + bias sums ----------------
__global__ __launch_bounds__(256) void k_wprep(const float* __restrict__ W1,
                                               const float* __restrict__ b1,
                                               const float* __restrict__ W2,
                                               const float* __restrict__ b2,
                                               unsigned short* __restrict__ Wb,
                                               float* __restrict__ bsum) {
    int idx = blockIdx.x * 256 + threadIdx.x;
    if (idx < 3 * 64 * 128) {
        int l = idx >> 13, rem = idx & 8191;
        int n = rem >> 7, k = rem & 127;
        float w = (k < 64) ? W1[l * 4096 + n * 64 + k] : W2[l * 4096 + n * 64 + (k - 64)];
        Wb[idx] = f2bf(w);
    } else if (idx < 3 * 64 * 128 + 192) {
        int t = idx - 3 * 64 * 128;
        bsum[t] = b1[t] + b2[t];
    }
}

// ---------------- bucket-level histogram (LDS-aggregated; 293 counters) ----------------
__global__ __launch_bounds__(256) void k_bkt_count(const int* __restrict__ rows,
                                                   int* __restrict__ bkt_count) {
    __shared__ int hist[NBKT];
    int tid = threadIdx.x;
    for (int t = tid; t < NBKT; t += 256) hist[t] = 0;
    __syncthreads();
    int e = (blockIdx.x * 256 + tid) * 4;
    if (e + 3 < N_EDGES) {
        int4 r = *(const int4*)&rows[e];
        atomicAdd(&hist[r.x >> BSHIFT], 1);
        atomicAdd(&hist[r.y >> BSHIFT], 1);
        atomicAdd(&hist[r.z >> BSHIFT], 1);
        atomicAdd(&hist[r.w >> BSHIFT], 1);
    } else {
        for (int k = 0; k < 4; k++)
            if (e + k < N_EDGES) atomicAdd(&hist[rows[e + k] >> BSHIFT], 1);
    }
    __syncthreads();
    for (int t = tid; t < NBKT; t += 256)
        if (hist[t] > 0) atomicAdd(&bkt_count[t], hist[t]);
}

// ---------------- scan of 293 bucket counts (1 block, 512 threads) ----------------
__global__ __launch_bounds__(512) void k_bkt_scan(const int* __restrict__ bkt_count,
                                                  int* __restrict__ bkt_base,
                                                  int* __restrict__ bkt_cursor,
                                                  int* __restrict__ row_ptr) {
    int tid = threadIdx.x;
    int x = (tid < NBKT) ? bkt_count[tid] : 0;
    int lane = tid & 63, wid = tid >> 6;
    int v = x;
    for (int o = 1; o < 64; o <<= 1) {
        int t = __shfl_up(v, o);
        if (lane >= o) v += t;
    }
    __shared__ int wsum[8];
    if (lane == 63) wsum[wid] = v;
    __syncthreads();
    int add = 0;
    for (int w = 0; w < wid; w++) add += wsum[w];
    int incl = add + v;
    int excl = incl - x;
    if (tid < NBKT) {
        bkt_base[tid]   = excl;
        bkt_cursor[tid] = excl;
    }
    if (tid == NBKT - 1) {
        bkt_base[NBKT]    = incl;          // == N_EDGES
        row_ptr[N_NODES]  = incl;
    }
}

// ---------------- Phase A: bucket edges (packed lr|col,val int2) ----------------
__global__ __launch_bounds__(256) void k_bucketA(const int* __restrict__ rows,
                                                 const int* __restrict__ cols,
                                                 const float* __restrict__ vals,
                                                 int* __restrict__ bkt_cursor,
                                                 int2* __restrict__ bucketed) {
    __shared__ int sr[EPB];
    __shared__ int sc[EPB];
    __shared__ int sv[EPB];
    __shared__ int hist[NBKT];
    __shared__ int cbase[NBKT];
    int tid = threadIdx.x;
    int e0 = blockIdx.x * EPB;
    int cnt = N_EDGES - e0; if (cnt > EPB) cnt = EPB;

    for (int i = tid; i < cnt; i += 256) {
        sr[i] = rows[e0 + i];
        sc[i] = cols[e0 + i];
        sv[i] = __float_as_int(vals[e0 + i]);
    }
    for (int t = tid; t < NBKT; t += 256) hist[t] = 0;
    __syncthreads();
    for (int i = tid; i < cnt; i += 256) atomicAdd(&hist[sr[i] >> BSHIFT], 1);
    __syncthreads();
    for (int t = tid; t < NBKT; t += 256)
        cbase[t] = (hist[t] > 0) ? atomicAdd(&bkt_cursor[t], hist[t]) : 0;
    __syncthreads();
    for (int t = tid; t < NBKT; t += 256) hist[t] = 0;
    __syncthreads();
    for (int i = tid; i < cnt; i += 256) {
        int r = sr[i];
        int b = r >> BSHIFT;
        int lr = r & (BROWS - 1);
        int off = atomicAdd(&hist[b], 1);
        bucketed[cbase[b] + off] = make_int2((lr << 18) | sc[i], sv[i]);
    }
}

// ---------------- Phase C: per-bucket row_ptr build + scatter (LDS atomics only) -------
__global__ __launch_bounds__(1024) void k_bucketC(const int* __restrict__ bkt_base,
                                                  const int2* __restrict__ bucketed,
                                                  int* __restrict__ row_ptr,
                                                  int2* __restrict__ edges) {
    __shared__ int hist[BROWS];
    __shared__ int ssum[BROWS];
    __shared__ int cur[BROWS];
    int b = blockIdx.x, tid = threadIdx.x;
    int base = bkt_base[b];
    int cnt  = bkt_base[b + 1] - base;
    int row0 = b << BSHIFT;

    if (tid < BROWS) hist[tid] = 0;
    __syncthreads();
    for (int i = tid; i < cnt; i += 1024)
        atomicAdd(&hist[bucketed[base + i].x >> 18], 1);
    __syncthreads();
    int own = 0;
    if (tid < BROWS) { own = hist[tid]; ssum[tid] = own; }
    __syncthreads();
    for (int off = 1; off < BROWS; off <<= 1) {
        int t = 0;
        if (tid < BROWS && tid >= off) t = ssum[tid - off];
        __syncthreads();
        if (tid < BROWS) ssum[tid] += t;
        __syncthreads();
    }
    if (tid < BROWS) {
        int excl = ssum[tid] - own;
        int grow = row0 + tid;
        if (grow < N_NODES) row_ptr[grow] = base + excl;
        cur[tid] = excl;
    }
    __syncthreads();
    for (int i = tid; i < cnt; i += 1024) {
        int2 ed = bucketed[base + i];
        int lr  = ed.x >> 18;
        int off = atomicAdd(&cur[lr], 1);
        edges[base + off] = make_int2(ed.x & 0x3ffff, ed.y);
    }
}

// ---------------- SpMM: 16 edge slots x 4 lanes (16B fp8 per lane) ----------------
// Doubles outstanding gathers per wave vs the 8-slot layout (latency-bound regime).
__global__ __launch_bounds__(256) void k_spmm(const int*  __restrict__ row_ptr,
                                              const int2* __restrict__ edges,
                                              const unsigned char* __restrict__ q8,
                                              unsigned short* __restrict__ t1eH) {
    int wave = threadIdx.x >> 6, lane = threadIdx.x & 63;
    int row = blockIdx.x * 4 + wave;                     // grid = 37500 exact
    int slot = lane >> 2;                                // 0..15 : edge slot
    int sl   = lane & 3;                                 // bytes 16*sl .. 16*sl+15
    int s = row_ptr[row], e = row_ptr[row + 1];
    float acc[16] = {};
    for (int p = s + slot; p < e; p += 16) {
        int2  ed = edges[p];
        uint4 w  = *(const uint4*)&q8[ed.x * EMBED + 16 * sl];
        qacc16(w, __int_as_float(ed.y), acc);
    }
    // combine the 16 edge slots (lanes differing in bits 2..5)
#pragma unroll
    for (int k = 0; k < 16; k++) {
        acc[k] += __shfl_xor(acc[k], 4);
        acc[k] += __shfl_xor(acc[k], 8);
        acc[k] += __shfl_xor(acc[k], 16);
        acc[k] += __shfl_xor(acc[k], 32);
    }
    if (slot == 0) {                                     // lanes 0..3 store 32B each
        uint4 o0, o1;
        o0.x = (unsigned)f2bf(acc[0])  | ((unsigned)f2bf(acc[1])  << 16);
        o0.y = (unsigned)f2bf(acc[2])  | ((unsigned)f2bf(acc[3])  << 16);
        o0.z = (unsigned)f2bf(acc[4])  | ((unsigned)f2bf(acc[5])  << 16);
        o0.w = (unsigned)f2bf(acc[6])  | ((unsigned)f2bf(acc[7])  << 16);
        o1.x = (unsigned)f2bf(acc[8])  | ((unsigned)f2bf(acc[9])  << 16);
        o1.y = (unsigned)f2bf(acc[10]) | ((unsigned)f2bf(acc[11]) << 16);
        o1.z = (unsigned)f2bf(acc[12]) | ((unsigned)f2bf(acc[13]) << 16);
        o1.w = (unsigned)f2bf(acc[14]) | ((unsigned)f2bf(acc[15]) << 16);
        *(uint4*)&t1eH[row * EMBED + 16 * sl]     = o0;
        *(uint4*)&t1eH[row * EMBED + 16 * sl + 8] = o1;
    }
}

__device__ __forceinline__ int map_row(int bb, const int* u, const int* ii, const int* jj) {
    if (bb < BATCH) return u[bb];
    if (bb < 2 * BATCH) return N_USERS + ii[bb - BATCH];
    return N_USERS + jj[bb - 2 * BATCH];
}

// ---------------- truncated SpMM: only the 24576 batch-needed rows --------------------
__global__ __launch_bounds__(256) void k_spmm_t(const int*  __restrict__ row_ptr,
                                                const int2* __restrict__ edges,
                                                const unsigned char* __restrict__ q8,
                                                unsigned short* __restrict__ t1eS,
                                                const int* __restrict__ u,
                                                const int* __restrict__ ii,
                                                const int* __restrict__ jj) {
    int wave = threadIdx.x >> 6, lane = threadIdx.x & 63;
    int bb = blockIdx.x * 4 + wave;                      // grid = 6144 exact
    int row = map_row(bb, u, ii, jj);
    int slot = lane >> 2, sl = lane & 3;
    int s = row_ptr[row], e = row_ptr[row + 1];
    float acc[16] = {};
    for (int p = s + slot; p < e; p += 16) {
        int2  ed = edges[p];
        uint4 w  = *(const uint4*)&q8[ed.x * EMBED + 16 * sl];
        qacc16(w, __int_as_float(ed.y), acc);
    }
#pragma unroll
    for (int k = 0; k < 16; k++) {
        acc[k] += __shfl_xor(acc[k], 4);
        acc[k] += __shfl_xor(acc[k], 8);
        acc[k] += __shfl_xor(acc[k], 16);
        acc[k] += __shfl_xor(acc[k], 32);
    }
    if (slot == 0) {
        uint4 o0, o1;
        o0.x = (unsigned)f2bf(acc[0])  | ((unsigned)f2bf(acc[1])  << 16);
        o0.y = (unsigned)f2bf(acc[2])  | ((unsigned)f2bf(acc[3])  << 16);
        o0.z = (unsigned)f2bf(acc[4])  | ((unsigned)f2bf(acc[5])  << 16);
        o0.w = (unsigned)f2bf(acc[6])  | ((unsigned)f2bf(acc[7])  << 16);
        o1.x = (unsigned)f2bf(acc[8])  | ((unsigned)f2bf(acc[9])  << 16);
        o1.y = (unsigned)f2bf(acc[10]) | ((unsigned)f2bf(acc[11]) << 16);
        o1.z = (unsigned)f2bf(acc[12]) | ((unsigned)f2bf(acc[13]) << 16);
        o1.w = (unsigned)f2bf(acc[14]) | ((unsigned)f2bf(acc[15]) << 16);
        *(uint4*)&t1eS[bb * EMBED + 16 * sl]     = o0;
        *(uint4*)&t1eS[bb * EMBED + 16 * sl + 8] = o1;
    }
}

// ---------------- dense via MFMA; writes bf16 out + fp8 shadow ----------------
__global__ __launch_bounds__(256) void k_dense(const unsigned short* __restrict__ t1eH,
                                               const unsigned short* __restrict__ embH_in,
                                               unsigned short* __restrict__ embH_out,
                                               unsigned char* __restrict__ q8out,
                                               const unsigned short* __restrict__ Wb,
                                               const float* __restrict__ bsum) {
    int tid  = threadIdx.x;
    int wave = tid >> 6, lane = tid & 63;
    int r16  = lane & 15, hi = lane >> 4;
    int rowt0 = blockIdx.x * 64 + wave * 16;
    int row   = rowt0 + r16;
    bool ok   = row < N_NODES;

    uint4 z4 = make_uint4(0u, 0u, 0u, 0u);
    const unsigned short* trow = t1eH    + (size_t)row * EMBED;
    const unsigned short* erow = embH_in + (size_t)row * EMBED;
    uint4 t_lo = ok ? *(const uint4*)(trow + hi * 8)      : z4;
    uint4 t_hi = ok ? *(const uint4*)(trow + 32 + hi * 8) : z4;
    uint4 e_lo = ok ? *(const uint4*)(erow + hi * 8)      : z4;
    uint4 e_hi = ok ? *(const uint4*)(erow + 32 + hi * 8) : z4;

    bf16x8 A0 = as_bf8(t_lo);
    bf16x8 A1 = as_bf8(t_hi);
    float ta[8], ea[8], pa[8];
    unpack8(t_lo, ta); unpack8(e_lo, ea);
#pragma unroll
    for (int j = 0; j < 8; j++) pa[j] = ta[j] * ea[j];
    bf16x8 A2 = pack8(pa);
    unpack8(t_hi, ta); unpack8(e_hi, ea);
#pragma unroll
    for (int j = 0; j < 8; j++) pa[j] = ta[j] * ea[j];
    bf16x8 A3 = pack8(pa);

#pragma unroll
    for (int nt = 0; nt < 4; nt++) {
        int wrow = nt * 16 + r16;
        const unsigned short* wp = Wb + wrow * 128 + hi * 8;
        bf16x8 B0 = as_bf8(*(const uint4*)(wp));
        bf16x8 B1 = as_bf8(*(const uint4*)(wp + 32));
        bf16x8 B2 = as_bf8(*(const uint4*)(wp + 64));
        bf16x8 B3 = as_bf8(*(const uint4*)(wp + 96));
        f32x4 c = {0.f, 0.f, 0.f, 0.f};
        c = __builtin_amdgcn_mfma_f32_16x16x32_bf16(A0, B0, c, 0, 0, 0);
        c = __builtin_amdgcn_mfma_f32_16x16x32_bf16(A1, B1, c, 0, 0, 0);
        c = __builtin_amdgcn_mfma_f32_16x16x32_bf16(A2, B2, c, 0, 0, 0);
        c = __builtin_amdgcn_mfma_f32_16x16x32_bf16(A3, B3, c, 0, 0, 0);

        int col = nt * 16 + r16;
        float bias = bsum[col];
#pragma unroll
        for (int r = 0; r < 4; r++) {
            int orow = rowt0 + hi * 4 + r;
            if (orow < N_NODES) {
                float v = c[r] + bias;
                v = (v > 0.f) ? v : 0.01f * v;
                embH_out[(size_t)orow * EMBED + col] = f2bf(v);
                q8out[(size_t)orow * EMBED + col]    = f2q8(v);
            }
        }
    }
}

// ---------------- truncated dense: 24576 batch rows ----------------
__global__ __launch_bounds__(256) void k_dense_t(const unsigned short* __restrict__ t1eS,
                                                 const unsigned short* __restrict__ embH_in,
                                                 unsigned short* __restrict__ t2out,
                                                 const unsigned short* __restrict__ Wb,
                                                 const float* __restrict__ bsum,
                                                 const int* __restrict__ u,
                                                 const int* __restrict__ ii,
                                                 const int* __restrict__ jj) {
    int tid  = threadIdx.x;
    int wave = tid >> 6, lane = tid & 63;
    int r16  = lane & 15, hi = lane >> 4;
    int rowt0 = blockIdx.x * 64 + wave * 16;             // grid = 384 exact -> bb < 24576
    int bb   = rowt0 + r16;
    int nrow = map_row(bb, u, ii, jj);

    const unsigned short* trow = t1eS    + (size_t)bb   * EMBED;
    const unsigned short* erow = embH_in + (size_t)nrow * EMBED;
    uint4 t_lo = *(const uint4*)(trow + hi * 8);
    uint4 t_hi = *(const uint4*)(trow + 32 + hi * 8);
    uint4 e_lo = *(const uint4*)(erow + hi * 8);
    uint4 e_hi = *(const uint4*)(erow + 32 + hi * 8);

    bf16x8 A0 = as_bf8(t_lo);
    bf16x8 A1 = as_bf8(t_hi);
    float ta[8], ea[8], pa[8];
    unpack8(t_lo, ta); unpack8(e_lo, ea);
#pragma unroll
    for (int j = 0; j < 8; j++) pa[j] = ta[j] * ea[j];
    bf16x8 A2 = pack8(pa);
    unpack8(t_hi, ta); unpack8(e_hi, ea);
#pragma unroll
    for (int j = 0; j < 8; j++) pa[j] = ta[j] * ea[j];
    bf16x8 A3 = pack8(pa);

#pragma unroll
    for (int nt = 0; nt < 4; nt++) {
        int wrow = nt * 16 + r16;
        const unsigned short* wp = Wb + wrow * 128 + hi * 8;
        bf16x8 B0 = as_bf8(*(const uint4*)(wp));
        bf16x8 B1 = as_bf8(*(const uint4*)(wp + 32));
        bf16x8 B2 = as_bf8(*(const uint4*)(wp + 64));
        bf16x8 B3 = as_bf8(*(const uint4*)(wp + 96));
        f32x4 c = {0.f, 0.f, 0.f, 0.f};
        c = __builtin_amdgcn_mfma_f32_16x16x32_bf16(A0, B0, c, 0, 0, 0);
        c = __builtin_amdgcn_mfma_f32_16x16x32_bf16(A1, B1, c, 0, 0, 0);
        c = __builtin_amdgcn_mfma_f32_16x16x32_bf16(A2, B2, c, 0, 0, 0);
        c = __builtin_amdgcn_mfma_f32_16x16x32_bf16(A3, B3, c, 0, 0, 0);

        int col = nt * 16 + r16;
        float bias = bsum[col];
#pragma unroll
        for (int r = 0; r < 4; r++) {
            int obb = rowt0 + hi * 4 + r;
            float v = c[r] + bias;
            v = (v > 0.f) ? v : 0.01f * v;
            t2out[(size_t)obb * EMBED + col] = f2bf(v);
        }
    }
}

// ---------------- scoring ----------------
__global__ __launch_bounds__(256) void k_score0(const float* __restrict__ ue,
                                                const float* __restrict__ ie,
                                                const int* __restrict__ u,
                                                const int* __restrict__ ii,
                                                const int* __restrict__ jj,
                                                float* __restrict__ posAcc,
                                                float* __restrict__ negAcc) {
    int wave = threadIdx.x >> 6, lane = threadIdx.x & 63;
    int b = blockIdx.x * 4 + wave;                       // grid = 2048 exact
    float eu = ue[u[b]  * EMBED + lane];
    float ep = ie[ii[b] * EMBED + lane];
    float en = ie[jj[b] * EMBED + lane];
    float p = eu * ep, n = eu * en;
    for (int o = 1; o < 64; o <<= 1) {
        p += __shfl_xor(p, o);
        n += __shfl_xor(n, o);
    }
    if (lane == 0) {
        posAcc[b] += p;
        negAcc[b] += n;
    }
}

__global__ __launch_bounds__(256) void k_score1(const unsigned short* __restrict__ tab,
                                                const int* __restrict__ u,
                                                const int* __restrict__ ii,
                                                const int* __restrict__ jj,
                                                float* __restrict__ posAcc,
                                                float* __restrict__ negAcc) {
    int wave = threadIdx.x >> 6, lane = threadIdx.x & 63;
    int b = blockIdx.x * 4 + wave;                       // grid = 2048 exact
    int ru = u[b];
    int ri = N_USERS + ii[b];
    int rj = N_USERS + jj[b];
    float eu = bf2f(tab[ru * EMBED + lane]);
    float ep = bf2f(tab[ri * EMBED + lane]);
    float en = bf2f(tab[rj * EMBED + lane]);
    float su = eu * eu, sp = ep * ep, sn = en * en;
    for (int o = 1; o < 64; o <<= 1) {
        su += __shfl_xor(su, o);
        sp += __shfl_xor(sp, o);
        sn += __shfl_xor(sn, o);
    }
    eu /= fmaxf(sqrtf(su), 1e-12f);
    ep /= fmaxf(sqrtf(sp), 1e-12f);
    en /= fmaxf(sqrtf(sn), 1e-12f);
    float p = eu * ep, n = eu * en;
    for (int o = 1; o < 64; o <<= 1) {
        p += __shfl_xor(p, o);
        n += __shfl_xor(n, o);
    }
    if (lane == 0) {
        posAcc[b] += p;
        negAcc[b] += n;
    }
}

// truncated-layer scoring: sequential reads of t2out rows (b, B+b, 2B+b)
__global__ __launch_bounds__(256) void k_score1t(const unsigned short* __restrict__ t2out,
                                                 float* __restrict__ posAcc,
                                                 float* __restrict__ negAcc) {
    int wave = threadIdx.x >> 6, lane = threadIdx.x & 63;
    int b = blockIdx.x * 4 + wave;                       // grid = 2048 exact
    float eu = bf2f(t2out[(size_t)b * EMBED + lane]);
    float ep = bf2f(t2out[(size_t)(BATCH + b) * EMBED + lane]);
    float en = bf2f(t2out[(size_t)(2 * BATCH + b) * EMBED + lane]);
    float su = eu * eu, sp = ep * ep, sn = en * en;
    for (int o = 1; o < 64; o <<= 1) {
        su += __shfl_xor(su, o);
        sp += __shfl_xor(sp, o);
        sn += __shfl_xor(sn, o);
    }
    eu /= fmaxf(sqrtf(su), 1e-12f);
    ep /= fmaxf(sqrtf(sp), 1e-12f);
    en /= fmaxf(sqrtf(sn), 1e-12f);
    float p = eu * ep, n = eu * en;
    for (int o = 1; o < 64; o <<= 1) {
        p += __shfl_xor(p, o);
        n += __shfl_xor(n, o);
    }
    if (lane == 0) {
        posAcc[b] += p;
        negAcc[b] += n;
    }
}

// ---------------- final loss ----------------
__global__ __launch_bounds__(256) void k_loss(const float* __restrict__ pa,
                                              const float* __restrict__ na,
                                              float* __restrict__ out) {
    int b = blockIdx.x * 256 + threadIdx.x;              // grid = 32 exact
    float z = pa[b] - na[b];
    float x = -z;
    float sp = fmaxf(x, 0.f) + log1pf(expf(-fabsf(x)));  // softplus(-z)
    for (int o = 1; o < 64; o <<= 1) sp += __shfl_xor(sp, o);
    __shared__ float s[4];
    int wave = threadIdx.x >> 6, lane = threadIdx.x & 63;
    if (lane == 0) s[wave] = sp;
    __syncthreads();
    if (threadIdx.x == 0) {
        float t = s[0] + s[1] + s[2] + s[3];
        atomicAdd(out, t * (1.f / (float)BATCH));
    }
}

extern "C" void kernel_launch(void* const* d_in, const int* in_sizes, int n_in,
                              void* d_out, int out_size, void* d_ws, size_t ws_size,
                              hipStream_t stream) {
    const float* user_emb = (const float*)d_in[0];
    const float* item_emb = (const float*)d_in[1];
    const float* W1       = (const float*)d_in[2];
    const float* b1       = (const float*)d_in[3];
    const float* W2       = (const float*)d_in[4];
    const float* b2       = (const float*)d_in[5];
    const float* adj_vals = (const float*)d_in[6];
    const int*   adj_rows = (const int*)d_in[7];
    const int*   adj_cols = (const int*)d_in[8];
    const int*   u_idx    = (const int*)d_in[9];
    const int*   i_idx    = (const int*)d_in[10];
    const int*   j_idx    = (const int*)d_in[11];
    float* out = (float*)d_out;

    // workspace layout (bytes) — 94,065,664 total (validated footprint)
    // region [0, 38,400,000): time-shared:
    //   CSR (first):  bucketed int2[2M] @ +0 (16,000,000), bkt_* @ +32,000,000..
    //   layers (after): t1eH @ +0 (19.2M); t1eS @ +0 / t2out @ +4M (layer 2);
    //                   Wb @ +20,000,000; bsum @ +20,100,000; Q8 @ +20,200,000 (9.6M)
    char* ws = (char*)d_ws;
    unsigned short* t1eH       = (unsigned short*)(ws);
    unsigned short* t1eS       = (unsigned short*)(ws);               // 3,145,728 B
    unsigned short* t2out      = (unsigned short*)(ws + 4000000);     // 3,145,728 B
    int2*           bucketed   = (int2*)(ws);                         // 16,000,000 B
    unsigned short* Wb         = (unsigned short*)(ws + 20000000);    // 49,152 B
    float*          bsum       = (float*)(ws + 20100000);             // 768 B
    unsigned char*  Q8         = (unsigned char*)(ws + 20200000);     // 9,600,000 B
    int*            bkt_count  = (int*)(ws + 32000000);               // 293 ints
    int*            bkt_base   = (int*)(ws + 32004096);               // 294 ints
    int*            bkt_cursor = (int*)(ws + 32008192);               // 293 ints
    unsigned short* HA         = (unsigned short*)(ws + 38400000);    // 19,200,000
    unsigned short* HB         = (unsigned short*)(ws + 57600000);    // 19,200,000
    int*            row_ptr    = (int*)(ws + 76800000);               // 600,004
    int2*           edges      = (int2*)(ws + 78000128);              // 16,000,000
    float*          posAcc     = (float*)(ws + 94000128);             // 32,768
    float*          negAcc     = (float*)(ws + 94032896);             // 32,768

    hipMemsetAsync(bkt_count, 0, 4096, stream);
    hipMemsetAsync(posAcc, 0, 2 * BATCH * sizeof(float), stream);    // covers negAcc too
    hipMemsetAsync(d_out, 0, sizeof(float), stream);

    // CSR build FIRST (bucketed region is then dead and reused by Wb/Q8)
    k_bkt_count<<<(N_EDGES / 4 + 255) / 256, 256, 0, stream>>>(adj_rows, bkt_count);
    k_bkt_scan<<<1, 512, 0, stream>>>(bkt_count, bkt_base, bkt_cursor, row_ptr);
    k_bucketA<<<(N_EDGES + EPB - 1) / EPB, 256, 0, stream>>>(adj_rows, adj_cols, adj_vals,
                                                             bkt_cursor, bucketed);
    k_bucketC<<<NBKT, 1024, 0, stream>>>(bkt_base, bucketed, row_ptr, edges);

    // weights + tables
    k_wprep<<<97, 256, 0, stream>>>(W1, b1, W2, b2, Wb, bsum);
    k_tabs<<<(N_NODES * EMBED / 4 + 255) / 256, 256, 0, stream>>>(
        (const float4*)user_emb, (const float4*)item_emb, (ushort4*)HA, (unsigned int*)Q8);

    // layer-0 scoring on raw f32 inputs (exact)
    k_score0<<<BATCH / 4, 256, 0, stream>>>(user_emb, item_emb, u_idx, i_idx, j_idx,
                                            posAcc, negAcc);

    const int SGRID = N_NODES / 4;        // 37500 (wave per row)
    const int DGRID = (N_NODES + 63) / 64;

    // layer 0: Q8(raw) -> t1eH; dense -> HB + Q8(HB)
    k_spmm<<<SGRID, 256, 0, stream>>>(row_ptr, edges, Q8, t1eH);
    k_dense<<<DGRID, 256, 0, stream>>>(t1eH, HA, HB, Q8, Wb, bsum);
    k_score1<<<BATCH / 4, 256, 0, stream>>>(HB, u_idx, i_idx, j_idx, posAcc, negAcc);

    // layer 1: Q8(HB) -> t1eH; dense -> HA + Q8(HA)
    k_spmm<<<SGRID, 256, 0, stream>>>(row_ptr, edges, Q8, t1eH);
    k_dense<<<DGRID, 256, 0, stream>>>(t1eH, HB, HA, Q8, Wb + 8192, bsum + 64);
    k_score1<<<BATCH / 4, 256, 0, stream>>>(HA, u_idx, i_idx, j_idx, posAcc, negAcc);

    // layer 2 (truncated): Q8(HA) -> t1eS -> t2out for the 24576 batch rows
    k_spmm_t<<<BATCH3 / 4, 256, 0, stream>>>(row_ptr, edges, Q8, t1eS,
                                             u_idx, i_idx, j_idx);
    k_dense_t<<<BATCH3 / 64, 256, 0, stream>>>(t1eS, HA, t2out, Wb + 16384, bsum + 128,
                                               u_idx, i_idx, j_idx);
    k_score1t<<<BATCH / 4, 256, 0, stream>>>(t2out, posAcc, negAcc);

    k_loss<<<BATCH / 256, 256, 0, stream>>>(posAcc, negAcc, out);
}

// Round 14
// 340.347 us; speedup vs baseline: 1.2994x; 1.2994x over previous
//
#include <hip/hip_runtime.h>
#include <hip/hip_bf16.h>
#include <math.h>

#define N_USERS 50000
#define N_ITEMS 100000
#define N_NODES 150000
#define N_EDGES 2000000
#define EMBED 64
#define N_LAYERS 3
#define BATCH 8192
#define BATCH3 (3 * BATCH)                                // 24576 truncated rows

#define BSHIFT 8
#define BROWS 256                                         // rows per bucket
#define NBKT ((N_NODES + BROWS - 1) / BROWS)              // 586
#define EPB 4096                                          // edges per phase-A block

typedef __bf16 bf16x8 __attribute__((ext_vector_type(8)));
typedef float  f32x4  __attribute__((ext_vector_type(4)));

__device__ __forceinline__ float bf2f(unsigned short u) {
    union { unsigned int i; float f; } c; c.i = ((unsigned int)u) << 16; return c.f;
}
__device__ __forceinline__ unsigned short f2bf(float f) {
    __hip_bfloat16 h = __float2bfloat16(f);               // RNE
    union { __hip_bfloat16 h; unsigned short u; } c; c.h = h; return c.u;
}
__device__ __forceinline__ unsigned char f2q8(float x) {  // f32 -> fp8 e4m3 (RNE)
    return (unsigned char)(__builtin_amdgcn_cvt_pk_fp8_f32(x, x, 0, false) & 0xff);
}
__device__ __forceinline__ bf16x8 as_bf8(uint4 u) {
    union { uint4 u; bf16x8 v; } c; c.u = u; return c.v;
}
__device__ __forceinline__ void unpack8(uint4 u, float* f) {
    union { unsigned int i; float x; } c;
    c.i = u.x << 16; f[0] = c.x; c.i = u.x & 0xffff0000u; f[1] = c.x;
    c.i = u.y << 16; f[2] = c.x; c.i = u.y & 0xffff0000u; f[3] = c.x;
    c.i = u.z << 16; f[4] = c.x; c.i = u.z & 0xffff0000u; f[5] = c.x;
    c.i = u.w << 16; f[6] = c.x; c.i = u.w & 0xffff0000u; f[7] = c.x;
}
__device__ __forceinline__ bf16x8 pack8(const float* f) {
    union { unsigned short s[8]; bf16x8 v; } u;
#pragma unroll
    for (int j = 0; j < 8; j++) u.s[j] = f2bf(f[j]);
    return u.v;
}
// fp8x8 (uint2) gather-accumulate: acc[0..7] += v * vals
__device__ __forceinline__ void qacc(uint2 w, float v, float* acc) {
    auto f0 = __builtin_amdgcn_cvt_pk_f32_fp8(w.x, false);
    auto f1 = __builtin_amdgcn_cvt_pk_f32_fp8(w.x, true);
    auto f2 = __builtin_amdgcn_cvt_pk_f32_fp8(w.y, false);
    auto f3 = __builtin_amdgcn_cvt_pk_f32_fp8(w.y, true);
    acc[0] += v * f0[0]; acc[1] += v * f0[1];
    acc[2] += v * f1[0]; acc[3] += v * f1[1];
    acc[4] += v * f2[0]; acc[5] += v * f2[1];
    acc[6] += v * f3[0]; acc[7] += v * f3[1];
}

// ---------------- build bf16 + fp8 tables from split f32 inputs ----------------
__global__ __launch_bounds__(256) void k_tabs(const float4* __restrict__ ue,
                                              const float4* __restrict__ ie,
                                              ushort4* __restrict__ tab,
                                              unsigned int* __restrict__ q8) {
    int idx = blockIdx.x * 256 + threadIdx.x;             // float4 index
    const int TOT = N_NODES * EMBED / 4;                  // 2,400,000
    const int UPART = N_USERS * EMBED / 4;                // 800,000
    if (idx < TOT) {
        float4 v = (idx < UPART) ? ue[idx] : ie[idx - UPART];
        ushort4 o;
        o.x = f2bf(v.x); o.y = f2bf(v.y); o.z = f2bf(v.z); o.w = f2bf(v.w);
        tab[idx] = o;
        unsigned int lo = (unsigned int)__builtin_amdgcn_cvt_pk_fp8_f32(v.x, v.y, 0, false) & 0xffffu;
        unsigned int hi = (unsigned int)__builtin_amdgcn_cvt_pk_fp8_f32(v.z, v.w, 0, false) & 0xffffu;
        q8[idx] = lo | (hi << 16);
    }
}

// ---------------- pack [W1;W2] into bf16 Wb[l][n][k0..127] + bias sums ----------------
__global__ __launch_bounds__(256) void k_wprep(const float* __restrict__ W1,
                                               const float* __restrict__ b1,
                                               const float* __restrict__ W2,
                                               const float* __restrict__ b2,
                                               unsigned short* __restrict__ Wb,
                                               float* __restrict__ bsum) {
    int idx = blockIdx.x * 256 + threadIdx.x;
    if (idx < 3 * 64 * 128) {
        int l = idx >> 13, rem = idx & 8191;
        int n = rem >> 7, k = rem & 127;
        float w = (k < 64) ? W1[l * 4096 + n * 64 + k] : W2[l * 4096 + n * 64 + (k - 64)];
        Wb[idx] = f2bf(w);
    } else if (idx < 3 * 64 * 128 + 192) {
        int t = idx - 3 * 64 * 128;
        bsum[t] = b1[t] + b2[t];
    }
}

// ---------------- bucket-level histogram (LDS-aggregated; 586 counters) ----------------
__global__ __launch_bounds__(256) void k_bkt_count(const int* __restrict__ rows,
                                                   int* __restrict__ bkt_count) {
    __shared__ int hist[NBKT];
    int tid = threadIdx.x;
    for (int t = tid; t < NBKT; t += 256) hist[t] = 0;
    __syncthreads();
    int e = (blockIdx.x * 256 + tid) * 4;
    if (e + 3 < N_EDGES) {
        int4 r = *(const int4*)&rows[e];
        atomicAdd(&hist[r.x >> BSHIFT], 1);
        atomicAdd(&hist[r.y >> BSHIFT], 1);
        atomicAdd(&hist[r.z >> BSHIFT], 1);
        atomicAdd(&hist[r.w >> BSHIFT], 1);
    } else {
        for (int k = 0; k < 4; k++)
            if (e + k < N_EDGES) atomicAdd(&hist[rows[e + k] >> BSHIFT], 1);
    }
    __syncthreads();
    for (int t = tid; t < NBKT; t += 256)
        if (hist[t] > 0) atomicAdd(&bkt_count[t], hist[t]);
}

// ---------------- scan of 586 bucket counts (1 block, 1024 threads) ----------------
__global__ __launch_bounds__(1024) void k_bkt_scan(const int* __restrict__ bkt_count,
                                                   int* __restrict__ bkt_base,
                                                   int* __restrict__ bkt_cursor,
                                                   int* __restrict__ row_ptr) {
    int tid = threadIdx.x;
    int x = (tid < NBKT) ? bkt_count[tid] : 0;
    int lane = tid & 63, wid = tid >> 6;
    int v = x;
    for (int o = 1; o < 64; o <<= 1) {
        int t = __shfl_up(v, o);
        if (lane >= o) v += t;
    }
    __shared__ int wsum[16];
    if (lane == 63) wsum[wid] = v;
    __syncthreads();
    int add = 0;
    for (int w = 0; w < wid; w++) add += wsum[w];
    int incl = add + v;
    int excl = incl - x;
    if (tid < NBKT) {
        bkt_base[tid]   = excl;
        bkt_cursor[tid] = excl;
    }
    if (tid == NBKT - 1) {
        bkt_base[NBKT]    = incl;          // == N_EDGES
        row_ptr[N_NODES]  = incl;
    }
}

// ---------------- Phase A: bucket edges (packed lr|col,val int2) ----------------
__global__ __launch_bounds__(256) void k_bucketA(const int* __restrict__ rows,
                                                 const int* __restrict__ cols,
                                                 const float* __restrict__ vals,
                                                 int* __restrict__ bkt_cursor,
                                                 int2* __restrict__ bucketed) {
    __shared__ int sr[EPB];
    __shared__ int sc[EPB];
    __shared__ int sv[EPB];
    __shared__ int hist[NBKT];
    __shared__ int cbase[NBKT];
    int tid = threadIdx.x;
    int e0 = blockIdx.x * EPB;
    int cnt = N_EDGES - e0; if (cnt > EPB) cnt = EPB;

    for (int i = tid; i < cnt; i += 256) {
        sr[i] = rows[e0 + i];
        sc[i] = cols[e0 + i];
        sv[i] = __float_as_int(vals[e0 + i]);
    }
    for (int t = tid; t < NBKT; t += 256) hist[t] = 0;
    __syncthreads();
    for (int i = tid; i < cnt; i += 256) atomicAdd(&hist[sr[i] >> BSHIFT], 1);
    __syncthreads();
    for (int t = tid; t < NBKT; t += 256)
        cbase[t] = (hist[t] > 0) ? atomicAdd(&bkt_cursor[t], hist[t]) : 0;
    __syncthreads();
    for (int t = tid; t < NBKT; t += 256) hist[t] = 0;
    __syncthreads();
    for (int i = tid; i < cnt; i += 256) {
        int r = sr[i];
        int b = r >> BSHIFT;
        int lr = r & (BROWS - 1);
        int off = atomicAdd(&hist[b], 1);
        bucketed[cbase[b] + off] = make_int2((lr << 18) | sc[i], sv[i]);
    }
}

// ---------------- Phase C: per-bucket row_ptr build + scatter (LDS atomics only) -------
__global__ __launch_bounds__(1024) void k_bucketC(const int* __restrict__ bkt_base,
                                                  const int2* __restrict__ bucketed,
                                                  int* __restrict__ row_ptr,
                                                  int2* __restrict__ edges) {
    __shared__ int hist[BROWS];
    __shared__ int ssum[BROWS];
    __shared__ int cur[BROWS];
    int b = blockIdx.x, tid = threadIdx.x;
    int base = bkt_base[b];
    int cnt  = bkt_base[b + 1] - base;
    int row0 = b << BSHIFT;

    if (tid < BROWS) hist[tid] = 0;
    __syncthreads();
    for (int i = tid; i < cnt; i += 1024)
        atomicAdd(&hist[bucketed[base + i].x >> 18], 1);
    __syncthreads();
    int own = 0;
    if (tid < BROWS) { own = hist[tid]; ssum[tid] = own; }
    __syncthreads();
    for (int off = 1; off < BROWS; off <<= 1) {
        int t = 0;
        if (tid < BROWS && tid >= off) t = ssum[tid - off];
        __syncthreads();
        if (tid < BROWS) ssum[tid] += t;
        __syncthreads();
    }
    if (tid < BROWS) {
        int excl = ssum[tid] - own;
        int grow = row0 + tid;
        if (grow < N_NODES) row_ptr[grow] = base + excl;
        cur[tid] = excl;
    }
    __syncthreads();
    for (int i = tid; i < cnt; i += 1024) {
        int2 ed = bucketed[base + i];
        int lr  = ed.x >> 18;
        int off = atomicAdd(&cur[lr], 1);
        edges[base + off] = make_int2(ed.x & 0x3ffff, ed.y);
    }
}

// ---------------- SpMM: t1eH = A @ emb (fp8 gather, wave/row, 8 slots, 2x unroll) -----
__global__ __launch_bounds__(256) void k_spmm(const int*  __restrict__ row_ptr,
                                              const int2* __restrict__ edges,
                                              const unsigned char* __restrict__ q8,
                                              unsigned short* __restrict__ t1eH) {
    int wave = threadIdx.x >> 6, lane = threadIdx.x & 63;
    int row = blockIdx.x * 4 + wave;                     // grid = 37500 exact
    int slot = lane >> 3;                                // 0..7 : edge slot
    int sl   = lane & 7;                                 // dims 8*sl .. 8*sl+7
    int s = row_ptr[row], e = row_ptr[row + 1];
    float acc[8] = {};
    int p = s + slot;
    for (; p + 8 < e; p += 16) {
        int2 ed0 = edges[p];
        int2 ed1 = edges[p + 8];
        uint2 w0 = *(const uint2*)&q8[ed0.x * EMBED + 8 * sl];
        uint2 w1 = *(const uint2*)&q8[ed1.x * EMBED + 8 * sl];
        qacc(w0, __int_as_float(ed0.y), acc);
        qacc(w1, __int_as_float(ed1.y), acc);
    }
    if (p < e) {
        int2 ed = edges[p];
        uint2 w = *(const uint2*)&q8[ed.x * EMBED + 8 * sl];
        qacc(w, __int_as_float(ed.y), acc);
    }
#pragma unroll
    for (int k = 0; k < 8; k++) {
        acc[k] += __shfl_xor(acc[k], 8);
        acc[k] += __shfl_xor(acc[k], 16);
        acc[k] += __shfl_xor(acc[k], 32);
    }
    if (slot == 0) {
        uint4 o;
        o.x = (unsigned)f2bf(acc[0]) | ((unsigned)f2bf(acc[1]) << 16);
        o.y = (unsigned)f2bf(acc[2]) | ((unsigned)f2bf(acc[3]) << 16);
        o.z = (unsigned)f2bf(acc[4]) | ((unsigned)f2bf(acc[5]) << 16);
        o.w = (unsigned)f2bf(acc[6]) | ((unsigned)f2bf(acc[7]) << 16);
        *(uint4*)&t1eH[row * EMBED + 8 * sl] = o;
    }
}

__device__ __forceinline__ int map_row(int bb, const int* u, const int* ii, const int* jj) {
    if (bb < BATCH) return u[bb];
    if (bb < 2 * BATCH) return N_USERS + ii[bb - BATCH];
    return N_USERS + jj[bb - 2 * BATCH];
}

// ---------------- truncated SpMM: only the 24576 batch-needed rows --------------------
__global__ __launch_bounds__(256) void k_spmm_t(const int*  __restrict__ row_ptr,
                                                const int2* __restrict__ edges,
                                                const unsigned char* __restrict__ q8,
                                                unsigned short* __restrict__ t1eS,
                                                const int* __restrict__ u,
                                                const int* __restrict__ ii,
                                                const int* __restrict__ jj) {
    int wave = threadIdx.x >> 6, lane = threadIdx.x & 63;
    int bb = blockIdx.x * 4 + wave;                      // grid = 6144 exact
    int row = map_row(bb, u, ii, jj);
    int slot = lane >> 3, sl = lane & 7;
    int s = row_ptr[row], e = row_ptr[row + 1];
    float acc[8] = {};
    int p = s + slot;
    for (; p + 8 < e; p += 16) {
        int2 ed0 = edges[p];
        int2 ed1 = edges[p + 8];
        uint2 w0 = *(const uint2*)&q8[ed0.x * EMBED + 8 * sl];
        uint2 w1 = *(const uint2*)&q8[ed1.x * EMBED + 8 * sl];
        qacc(w0, __int_as_float(ed0.y), acc);
        qacc(w1, __int_as_float(ed1.y), acc);
    }
    if (p < e) {
        int2 ed = edges[p];
        uint2 w = *(const uint2*)&q8[ed.x * EMBED + 8 * sl];
        qacc(w, __int_as_float(ed.y), acc);
    }
#pragma unroll
    for (int k = 0; k < 8; k++) {
        acc[k] += __shfl_xor(acc[k], 8);
        acc[k] += __shfl_xor(acc[k], 16);
        acc[k] += __shfl_xor(acc[k], 32);
    }
    if (slot == 0) {
        uint4 o;
        o.x = (unsigned)f2bf(acc[0]) | ((unsigned)f2bf(acc[1]) << 16);
        o.y = (unsigned)f2bf(acc[2]) | ((unsigned)f2bf(acc[3]) << 16);
        o.z = (unsigned)f2bf(acc[4]) | ((unsigned)f2bf(acc[5]) << 16);
        o.w = (unsigned)f2bf(acc[6]) | ((unsigned)f2bf(acc[7]) << 16);
        *(uint4*)&t1eS[bb * EMBED + 8 * sl] = o;
    }
}

// ---------------- dense via MFMA; writes bf16 out + fp8 shadow ----------------
__global__ __launch_bounds__(256) void k_dense(const unsigned short* __restrict__ t1eH,
                                               const unsigned short* __restrict__ embH_in,
                                               unsigned short* __restrict__ embH_out,
                                               unsigned char* __restrict__ q8out,
                                               const unsigned short* __restrict__ Wb,
                                               const float* __restrict__ bsum) {
    int tid  = threadIdx.x;
    int wave = tid >> 6, lane = tid & 63;
    int r16  = lane & 15, hi = lane >> 4;
    int rowt0 = blockIdx.x * 64 + wave * 16;
    int row   = rowt0 + r16;
    bool ok   = row < N_NODES;

    uint4 z4 = make_uint4(0u, 0u, 0u, 0u);
    const unsigned short* trow = t1eH    + (size_t)row * EMBED;
    const unsigned short* erow = embH_in + (size_t)row * EMBED;
    uint4 t_lo = ok ? *(const uint4*)(trow + hi * 8)      : z4;
    uint4 t_hi = ok ? *(const uint4*)(trow + 32 + hi * 8) : z4;
    uint4 e_lo = ok ? *(const uint4*)(erow + hi * 8)      : z4;
    uint4 e_hi = ok ? *(const uint4*)(erow + 32 + hi * 8) : z4;

    bf16x8 A0 = as_bf8(t_lo);
    bf16x8 A1 = as_bf8(t_hi);
    float ta[8], ea[8], pa[8];
    unpack8(t_lo, ta); unpack8(e_lo, ea);
#pragma unroll
    for (int j = 0; j < 8; j++) pa[j] = ta[j] * ea[j];
    bf16x8 A2 = pack8(pa);
    unpack8(t_hi, ta); unpack8(e_hi, ea);
#pragma unroll
    for (int j = 0; j < 8; j++) pa[j] = ta[j] * ea[j];
    bf16x8 A3 = pack8(pa);

#pragma unroll
    for (int nt = 0; nt < 4; nt++) {
        int wrow = nt * 16 + r16;
        const unsigned short* wp = Wb + wrow * 128 + hi * 8;
        bf16x8 B0 = as_bf8(*(const uint4*)(wp));
        bf16x8 B1 = as_bf8(*(const uint4*)(wp + 32));
        bf16x8 B2 = as_bf8(*(const uint4*)(wp + 64));
        bf16x8 B3 = as_bf8(*(const uint4*)(wp + 96));
        f32x4 c = {0.f, 0.f, 0.f, 0.f};
        c = __builtin_amdgcn_mfma_f32_16x16x32_bf16(A0, B0, c, 0, 0, 0);
        c = __builtin_amdgcn_mfma_f32_16x16x32_bf16(A1, B1, c, 0, 0, 0);
        c = __builtin_amdgcn_mfma_f32_16x16x32_bf16(A2, B2, c, 0, 0, 0);
        c = __builtin_amdgcn_mfma_f32_16x16x32_bf16(A3, B3, c, 0, 0, 0);

        int col = nt * 16 + r16;
        float bias = bsum[col];
#pragma unroll
        for (int r = 0; r < 4; r++) {
            int orow = rowt0 + hi * 4 + r;
            if (orow < N_NODES) {
                float v = c[r] + bias;
                v = (v > 0.f) ? v : 0.01f * v;
                embH_out[(size_t)orow * EMBED + col] = f2bf(v);
                q8out[(size_t)orow * EMBED + col]    = f2q8(v);
            }
        }
    }
}

// ---------------- truncated dense: 24576 batch rows ----------------
__global__ __launch_bounds__(256) void k_dense_t(const unsigned short* __restrict__ t1eS,
                                                 const unsigned short* __restrict__ embH_in,
                                                 unsigned short* __restrict__ t2out,
                                                 const unsigned short* __restrict__ Wb,
                                                 const float* __restrict__ bsum,
                                                 const int* __restrict__ u,
                                                 const int* __restrict__ ii,
                                                 const int* __restrict__ jj) {
    int tid  = threadIdx.x;
    int wave = tid >> 6, lane = tid & 63;
    int r16  = lane & 15, hi = lane >> 4;
    int rowt0 = blockIdx.x * 64 + wave * 16;             // grid = 384 exact -> bb < 24576
    int bb   = rowt0 + r16;
    int nrow = map_row(bb, u, ii, jj);

    const unsigned short* trow = t1eS    + (size_t)bb   * EMBED;
    const unsigned short* erow = embH_in + (size_t)nrow * EMBED;
    uint4 t_lo = *(const uint4*)(trow + hi * 8);
    uint4 t_hi = *(const uint4*)(trow + 32 + hi * 8);
    uint4 e_lo = *(const uint4*)(erow + hi * 8);
    uint4 e_hi = *(const uint4*)(erow + 32 + hi * 8);

    bf16x8 A0 = as_bf8(t_lo);
    bf16x8 A1 = as_bf8(t_hi);
    float ta[8], ea[8], pa[8];
    unpack8(t_lo, ta); unpack8(e_lo, ea);
#pragma unroll
    for (int j = 0; j < 8; j++) pa[j] = ta[j] * ea[j];
    bf16x8 A2 = pack8(pa);
    unpack8(t_hi, ta); unpack8(e_hi, ea);
#pragma unroll
    for (int j = 0; j < 8; j++) pa[j] = ta[j] * ea[j];
    bf16x8 A3 = pack8(pa);

#pragma unroll
    for (int nt = 0; nt < 4; nt++) {
        int wrow = nt * 16 + r16;
        const unsigned short* wp = Wb + wrow * 128 + hi * 8;
        bf16x8 B0 = as_bf8(*(const uint4*)(wp));
        bf16x8 B1 = as_bf8(*(const uint4*)(wp + 32));
        bf16x8 B2 = as_bf8(*(const uint4*)(wp + 64));
        bf16x8 B3 = as_bf8(*(const uint4*)(wp + 96));
        f32x4 c = {0.f, 0.f, 0.f, 0.f};
        c = __builtin_amdgcn_mfma_f32_16x16x32_bf16(A0, B0, c, 0, 0, 0);
        c = __builtin_amdgcn_mfma_f32_16x16x32_bf16(A1, B1, c, 0, 0, 0);
        c = __builtin_amdgcn_mfma_f32_16x16x32_bf16(A2, B2, c, 0, 0, 0);
        c = __builtin_amdgcn_mfma_f32_16x16x32_bf16(A3, B3, c, 0, 0, 0);

        int col = nt * 16 + r16;
        float bias = bsum[col];
#pragma unroll
        for (int r = 0; r < 4; r++) {
            int obb = rowt0 + hi * 4 + r;
            float v = c[r] + bias;
            v = (v > 0.f) ? v : 0.01f * v;
            t2out[(size_t)obb * EMBED + col] = f2bf(v);
        }
    }
}

// ---------------- scoring ----------------
__global__ __launch_bounds__(256) void k_score0(const float* __restrict__ ue,
                                                const float* __restrict__ ie,
                                                const int* __restrict__ u,
                                                const int* __restrict__ ii,
                                                const int* __restrict__ jj,
                                                float* __restrict__ posAcc,
                                                float* __restrict__ negAcc) {
    int wave = threadIdx.x >> 6, lane = threadIdx.x & 63;
    int b = blockIdx.x * 4 + wave;                       // grid = 2048 exact
    float eu = ue[u[b]  * EMBED + lane];
    float ep = ie[ii[b] * EMBED + lane];
    float en = ie[jj[b] * EMBED + lane];
    float p = eu * ep, n = eu * en;
    for (int o = 1; o < 64; o <<= 1) {
        p += __shfl_xor(p, o);
        n += __shfl_xor(n, o);
    }
    if (lane == 0) {
        posAcc[b] += p;
        negAcc[b] += n;
    }
}

__global__ __launch_bounds__(256) void k_score1(const unsigned short* __restrict__ tab,
                                                const int* __restrict__ u,
                                                const int* __restrict__ ii,
                                                const int* __restrict__ jj,
                                                float* __restrict__ posAcc,
                                                float* __restrict__ negAcc) {
    int wave = threadIdx.x >> 6, lane = threadIdx.x & 63;
    int b = blockIdx.x * 4 + wave;                       // grid = 2048 exact
    int ru = u[b];
    int ri = N_USERS + ii[b];
    int rj = N_USERS + jj[b];
    float eu = bf2f(tab[ru * EMBED + lane]);
    float ep = bf2f(tab[ri * EMBED + lane]);
    float en = bf2f(tab[rj * EMBED + lane]);
    float su = eu * eu, sp = ep * ep, sn = en * en;
    for (int o = 1; o < 64; o <<= 1) {
        su += __shfl_xor(su, o);
        sp += __shfl_xor(sp, o);
        sn += __shfl_xor(sn, o);
    }
    eu /= fmaxf(sqrtf(su), 1e-12f);
    ep /= fmaxf(sqrtf(sp), 1e-12f);
    en /= fmaxf(sqrtf(sn), 1e-12f);
    float p = eu * ep, n = eu * en;
    for (int o = 1; o < 64; o <<= 1) {
        p += __shfl_xor(p, o);
        n += __shfl_xor(n, o);
    }
    if (lane == 0) {
        posAcc[b] += p;
        negAcc[b] += n;
    }
}

// truncated-layer scoring: sequential reads of t2out rows (b, B+b, 2B+b)
__global__ __launch_bounds__(256) void k_score1t(const unsigned short* __restrict__ t2out,
                                                 float* __restrict__ posAcc,
                                                 float* __restrict__ negAcc) {
    int wave = threadIdx.x >> 6, lane = threadIdx.x & 63;
    int b = blockIdx.x * 4 + wave;                       // grid = 2048 exact
    float eu = bf2f(t2out[(size_t)b * EMBED + lane]);
    float ep = bf2f(t2out[(size_t)(BATCH + b) * EMBED + lane]);
    float en = bf2f(t2out[(size_t)(2 * BATCH + b) * EMBED + lane]);
    float su = eu * eu, sp = ep * ep, sn = en * en;
    for (int o = 1; o < 64; o <<= 1) {
        su += __shfl_xor(su, o);
        sp += __shfl_xor(sp, o);
        sn += __shfl_xor(sn, o);
    }
    eu /= fmaxf(sqrtf(su), 1e-12f);
    ep /= fmaxf(sqrtf(sp), 1e-12f);
    en /= fmaxf(sqrtf(sn), 1e-12f);
    float p = eu * ep, n = eu * en;
    for (int o = 1; o < 64; o <<= 1) {
        p += __shfl_xor(p, o);
        n += __shfl_xor(n, o);
    }
    if (lane == 0) {
        posAcc[b] += p;
        negAcc[b] += n;
    }
}

// ---------------- final loss ----------------
__global__ __launch_bounds__(256) void k_loss(const float* __restrict__ pa,
                                              const float* __restrict__ na,
                                              float* __restrict__ out) {
    int b = blockIdx.x * 256 + threadIdx.x;              // grid = 32 exact
    float z = pa[b] - na[b];
    float x = -z;
    float sp = fmaxf(x, 0.f) + log1pf(expf(-fabsf(x)));  // softplus(-z)
    for (int o = 1; o < 64; o <<= 1) sp += __shfl_xor(sp, o);
    __shared__ float s[4];
    int wave = threadIdx.x >> 6, lane = threadIdx.x & 63;
    if (lane == 0) s[wave] = sp;
    __syncthreads();
    if (threadIdx.x == 0) {
        float t = s[0] + s[1] + s[2] + s[3];
        atomicAdd(out, t * (1.f / (float)BATCH));
    }
}

extern "C" void kernel_launch(void* const* d_in, const int* in_sizes, int n_in,
                              void* d_out, int out_size, void* d_ws, size_t ws_size,
                              hipStream_t stream) {
    const float* user_emb = (const float*)d_in[0];
    const float* item_emb = (const float*)d_in[1];
    const float* W1       = (const float*)d_in[2];
    const float* b1       = (const float*)d_in[3];
    const float* W2       = (const float*)d_in[4];
    const float* b2       = (const float*)d_in[5];
    const float* adj_vals = (const float*)d_in[6];
    const int*   adj_rows = (const int*)d_in[7];
    const int*   adj_cols = (const int*)d_in[8];
    const int*   u_idx    = (const int*)d_in[9];
    const int*   i_idx    = (const int*)d_in[10];
    const int*   j_idx    = (const int*)d_in[11];
    float* out = (float*)d_out;

    // workspace layout (bytes) — 94,065,664 total (validated footprint)
    // region [0, 38,400,000): time-shared:
    //   CSR (first):  bucketed int2[2M] @ +0 (16,000,000), bkt_* @ +32,000,000..
    //   layers (after): t1eH @ +0 (19.2M); t1eS @ +0 / t2out @ +4M (layer 2);
    //                   Wb @ +20,000,000; bsum @ +20,100,000; Q8 @ +20,200,000 (9.6M)
    char* ws = (char*)d_ws;
    unsigned short* t1eH       = (unsigned short*)(ws);
    unsigned short* t1eS       = (unsigned short*)(ws);               // 3,145,728 B
    unsigned short* t2out      = (unsigned short*)(ws + 4000000);     // 3,145,728 B
    int2*           bucketed   = (int2*)(ws);                         // 16,000,000 B
    unsigned short* Wb         = (unsigned short*)(ws + 20000000);    // 49,152 B
    float*          bsum       = (float*)(ws + 20100000);             // 768 B
    unsigned char*  Q8         = (unsigned char*)(ws + 20200000);     // 9,600,000 B
    int*            bkt_count  = (int*)(ws + 32000000);               // 586 ints
    int*            bkt_base   = (int*)(ws + 32008192);               // 587 ints
    int*            bkt_cursor = (int*)(ws + 32016384);               // 586 ints
    unsigned short* HA         = (unsigned short*)(ws + 38400000);    // 19,200,000
    unsigned short* HB         = (unsigned short*)(ws + 57600000);    // 19,200,000
    int*            row_ptr    = (int*)(ws + 76800000);               // 600,004
    int2*           edges      = (int2*)(ws + 78000128);              // 16,000,000
    float*          posAcc     = (float*)(ws + 94000128);             // 32,768
    float*          negAcc     = (float*)(ws + 94032896);             // 32,768

    hipMemsetAsync(bkt_count, 0, 8192, stream);
    hipMemsetAsync(posAcc, 0, 2 * BATCH * sizeof(float), stream);    // covers negAcc too
    hipMemsetAsync(d_out, 0, sizeof(float), stream);

    // CSR build FIRST (bucketed region is then dead and reused by Wb/Q8)
    k_bkt_count<<<(N_EDGES / 4 + 255) / 256, 256, 0, stream>>>(adj_rows, bkt_count);
    k_bkt_scan<<<1, 1024, 0, stream>>>(bkt_count, bkt_base, bkt_cursor, row_ptr);
    k_bucketA<<<(N_EDGES + EPB - 1) / EPB, 256, 0, stream>>>(adj_rows, adj_cols, adj_vals,
                                                             bkt_cursor, bucketed);
    k_bucketC<<<NBKT, 1024, 0, stream>>>(bkt_base, bucketed, row_ptr, edges);

    // weights + tables
    k_wprep<<<97, 256, 0, stream>>>(W1, b1, W2, b2, Wb, bsum);
    k_tabs<<<(N_NODES * EMBED / 4 + 255) / 256, 256, 0, stream>>>(
        (const float4*)user_emb, (const float4*)item_emb, (ushort4*)HA, (unsigned int*)Q8);

    // layer-0 scoring on raw f32 inputs (exact)
    k_score0<<<BATCH / 4, 256, 0, stream>>>(user_emb, item_emb, u_idx, i_idx, j_idx,
                                            posAcc, negAcc);

    const int SGRID = N_NODES / 4;        // 37500 (wave per row)
    const int DGRID = (N_NODES + 63) / 64;

    // layer 0: Q8(raw) -> t1eH; dense -> HB + Q8(HB)
    k_spmm<<<SGRID, 256, 0, stream>>>(row_ptr, edges, Q8, t1eH);
    k_dense<<<DGRID, 256, 0, stream>>>(t1eH, HA, HB, Q8, Wb, bsum);
    k_score1<<<BATCH / 4, 256, 0, stream>>>(HB, u_idx, i_idx, j_idx, posAcc, negAcc);

    // layer 1: Q8(HB) -> t1eH; dense -> HA + Q8(HA)
    k_spmm<<<SGRID, 256, 0, stream>>>(row_ptr, edges, Q8, t1eH);
    k_dense<<<DGRID, 256, 0, stream>>>(t1eH, HB, HA, Q8, Wb + 8192, bsum + 64);
    k_score1<<<BATCH / 4, 256, 0, stream>>>(HA, u_idx, i_idx, j_idx, posAcc, negAcc);

    // layer 2 (truncated): Q8(HA) -> t1eS -> t2out for the 24576 batch rows
    k_spmm_t<<<BATCH3 / 4, 256, 0, stream>>>(row_ptr, edges, Q8, t1eS,
                                             u_idx, i_idx, j_idx);
    k_dense_t<<<BATCH3 / 64, 256, 0, stream>>>(t1eS, HA, t2out, Wb + 16384, bsum + 128,
                                               u_idx, i_idx, j_idx);
    k_score1t<<<BATCH / 4, 256, 0, stream>>>(t2out, posAcc, negAcc);

    k_loss<<<BATCH / 256, 256, 0, stream>>>(posAcc, negAcc, out);
}